// Round 3
// baseline (448.481 us; speedup 1.0000x reference)
//
#include <hip/hip_runtime.h>
#include <math.h>

// RandomActivation: out[r][c] = min(act(func_id[c], x[r][c]), max_output[c])
// BATCH=16384, DIM=4096, fp32 in/out. Memory-bound: 537 MB traffic, floor ~85us.
//
// v3 findings: measured dur_us includes ~330us of harness 1-GiB poison fills
// (rocprof top-5 = fillBufferAligned @165us; our kernel < 163us => ~104us).
// Kernel is memory-bound at ~5.2 TB/s effective. This version targets the
// memory path only: nontemporal loads/stores (x and out have zero reuse and
// together thrash the entire 256 MiB L3) + explicit 8-deep load batching for
// MLP. Activation math unchanged from v2 (branchless, shared __expf).
// (Round 2 was an infra failure — container died twice, no data; resubmit.)

#define RA_DIM   4096
#define RA_DIM4  (RA_DIM / 4)   // 1024, power of two
#define RA_BLOCK 256
#define RA_GRID  2048           // 524288 threads; stride is a multiple of RA_DIM4
#define RA_DEPTH 8              // loads in flight per unrolled pass

typedef float f32x4 __attribute__((ext_vector_type(4)));

__device__ __forceinline__ float ra_act_min(float v, int f, float m) {
    // Clamp so t*t can't overflow (e^88 -> inf); no-op for |v| < 44.
    float vc   = fminf(fmaxf(v, -44.0f), 44.0f);
    float t    = __expf(-vc);                                    // e^-v
    float sig  = __builtin_amdgcn_rcpf(1.0f + t);                // sigmoid
    float t2   = t * t;                                          // e^-2v
    float th   = (1.0f - t2) * __builtin_amdgcn_rcpf(1.0f + t2); // tanh
    float vmax = fmaxf(v, 0.0f);
    float silu = v * sig;
    float leak = vmax + 0.01f * fminf(v, 0.0f);

    float r = vmax;            // f==0: relu
    r = (f == 1) ? silu : r;   // v_cmp + v_cndmask each, no branches
    r = (f == 2) ? leak : r;
    r = (f == 3) ? sig  : r;
    r = (f == 4) ? th   : r;
    return fminf(r, m);
}

__global__ __launch_bounds__(RA_BLOCK) void RandomActivation_24567212933826_kernel(
        const f32x4* __restrict__ x4,
        const float4* __restrict__ mo4,   // max_output, [DIM4]
        const int4*   __restrict__ fid4,  // func_id,    [DIM4]
        f32x4* __restrict__ out4,
        int total4) {
    const int stride = RA_GRID * RA_BLOCK;           // 524288, multiple of RA_DIM4
    int tid = blockIdx.x * RA_BLOCK + threadIdx.x;   // 0 .. 524287
    int c4  = tid & (RA_DIM4 - 1);                   // fixed column group per thread

    // Column metadata loaded ONCE per thread (stride keeps c4 constant).
    int4   f = fid4[c4];
    float4 m = mo4[c4];

    // total4 = 16777216 => 32 iterations/thread = 4 passes of RA_DEPTH.
    int n_batches = total4 / (stride * RA_DEPTH);    // 4 for the fixed shape
    int idx = tid;

    for (int b = 0; b < n_batches; ++b) {
        f32x4 xv[RA_DEPTH];
        #pragma unroll
        for (int j = 0; j < RA_DEPTH; ++j)
            xv[j] = __builtin_nontemporal_load(&x4[idx + j * stride]);
        #pragma unroll
        for (int j = 0; j < RA_DEPTH; ++j) {
            f32x4 o;
            o.x = ra_act_min(xv[j].x, f.x, m.x);
            o.y = ra_act_min(xv[j].y, f.y, m.y);
            o.z = ra_act_min(xv[j].z, f.z, m.z);
            o.w = ra_act_min(xv[j].w, f.w, m.w);
            __builtin_nontemporal_store(o, &out4[idx + j * stride]);
        }
        idx += stride * RA_DEPTH;
    }

    // Tail (empty for the fixed 16384x4096 shape; kept for generality).
    for (; idx < total4; idx += stride) {
        f32x4 xv = __builtin_nontemporal_load(&x4[idx]);
        f32x4 o;
        o.x = ra_act_min(xv.x, f.x, m.x);
        o.y = ra_act_min(xv.y, f.y, m.y);
        o.z = ra_act_min(xv.z, f.z, m.z);
        o.w = ra_act_min(xv.w, f.w, m.w);
        __builtin_nontemporal_store(o, &out4[idx]);
    }
}

extern "C" void kernel_launch(void* const* d_in, const int* in_sizes, int n_in,
                              void* d_out, int out_size, void* d_ws, size_t ws_size,
                              hipStream_t stream) {
    const f32x4*  x4   = (const f32x4*)d_in[0];    // x [BATCH, DIM] fp32
    const float4* mo4  = (const float4*)d_in[1];   // max_output [DIM] fp32
    const int4*   fid4 = (const int4*)d_in[2];     // func_id [DIM] int32
    f32x4*        out4 = (f32x4*)d_out;

    long long total  = (long long)in_sizes[0];     // BATCH*DIM = 67108864
    int total4 = (int)(total / 4);                 // 16777216

    RandomActivation_24567212933826_kernel<<<dim3(RA_GRID), RA_BLOCK, 0, stream>>>(
        x4, mo4, fid4, out4, total4);
}